// Round 10
// baseline (911.722 us; speedup 1.0000x reference)
//
#include <hip/hip_runtime.h>

#define S 207
#define BATCH 128
#define NPTS 256000

static const int OFFS[19] = {0,8,16,24,32,40,56,72,88,104,128,152,176,200,232,264,296,328,392};

__global__ void zero2_kernel(float4* __restrict__ a, float4* __restrict__ b, int n4) {
    int i = blockIdx.x * blockDim.x + threadIdx.x;
    if (i < n4) { a[i] = make_float4(0,0,0,0); b[i] = make_float4(0,0,0,0); }
}

// zero two disjoint float4 ranges of different lengths
__global__ void zero_pair_kernel(float4* __restrict__ a, int n4a,
                                 float4* __restrict__ b, int n4b) {
    int i = blockIdx.x * blockDim.x + threadIdx.x;
    if (i < n4a) a[i] = make_float4(0,0,0,0);
    if (i < n4b) b[i] = make_float4(0,0,0,0);
}

__global__ void scatter_kernel(const int* __restrict__ loc, const int* __restrict__ bidx,
                               const float* __restrict__ feat,
                               float* __restrict__ xs, float* __restrict__ ms) {
    int t = blockIdx.x * blockDim.x + threadIdx.x;
    if (t >= NPTS) return;
    int b = bidx[t];
    int r = loc[2 * t];
    int c = loc[2 * t + 1];
    int idx = (b * S + r) * S + c;
    atomicAdd(&xs[idx], feat[t]);
    ms[idx] = 1.0f;
}

// Fused conv0(SAME)*m -> masked 3x2 maxpool. One thread per output pixel, all 8 channels.
__global__ __launch_bounds__(256) void conv0_pool_kernel(
    const float* __restrict__ xs, const float* __restrict__ ms,
    const float* __restrict__ w,   // (3,3,1,8)
    float* __restrict__ x1, float* __restrict__ m1) {
    const int Hout = 103;
    int opix = blockIdx.x * 256 + threadIdx.x;
    int total = BATCH * Hout * Hout;
    if (opix >= total) return;
    int wo = opix % Hout;
    int t = opix / Hout;
    int ho = t % Hout;
    int b  = t / Hout;

    float mv[3][3];
    float mwin = 0.0f;
    #pragma unroll
    for (int pi = 0; pi < 3; ++pi)
        #pragma unroll
        for (int pj = 0; pj < 3; ++pj) {
            float m = ms[(b * S + 2 * ho + pi) * S + 2 * wo + pj];
            mv[pi][pj] = m;
            mwin = fmaxf(mwin, m);
        }
    float* xp = x1 + (size_t)opix * 8;
    if (mwin <= 0.0f) {
        *(float4*)xp = make_float4(0,0,0,0);
        *(float4*)(xp + 4) = make_float4(0,0,0,0);
        m1[opix] = 0.0f;
        return;
    }
    float p[5][5];
    #pragma unroll
    for (int r = 0; r < 5; ++r) {
        int ii = 2 * ho - 1 + r;
        #pragma unroll
        for (int c = 0; c < 5; ++c) {
            int jj = 2 * wo - 1 + c;
            bool ok = ((unsigned)ii < (unsigned)S) && ((unsigned)jj < (unsigned)S);
            p[r][c] = ok ? xs[(b * S + ii) * S + jj] : 0.0f;
        }
    }
    float best[8];
    #pragma unroll
    for (int co = 0; co < 8; ++co) best[co] = -1e30f;
    #pragma unroll
    for (int pi = 0; pi < 3; ++pi)
        #pragma unroll
        for (int pj = 0; pj < 3; ++pj) {
            if (mv[pi][pj] > 0.0f) {
                float acc[8];
                #pragma unroll
                for (int co = 0; co < 8; ++co) acc[co] = 0.0f;
                #pragma unroll
                for (int kh = 0; kh < 3; ++kh)
                    #pragma unroll
                    for (int kw = 0; kw < 3; ++kw) {
                        float x = p[pi + kh][pj + kw];
                        #pragma unroll
                        for (int co = 0; co < 8; ++co)
                            acc[co] = fmaf(x, w[(kh * 3 + kw) * 8 + co], acc[co]);
                    }
                #pragma unroll
                for (int co = 0; co < 8; ++co) best[co] = fmaxf(best[co], acc[co]);
            }
        }
    *(float4*)xp = make_float4(best[0], best[1], best[2], best[3]);
    *(float4*)(xp + 4) = make_float4(best[4], best[5], best[6], best[7]);
    m1[opix] = 1.0f;
}

// Fused full residual block (stride 1, CIN==COUT==C), planar-LDS. C=8 only —
// measured: C=16 variant regresses (48 KB LDS -> 25% occ, 151 us; r7).
template <int C, int TILE, int NTX>
__global__ __launch_bounds__(256) void resblock_kernel(
    const float* __restrict__ in, const float* __restrict__ mask,
    const float* __restrict__ w1, const float* __restrict__ w2,
    const float* __restrict__ g1, const float* __restrict__ bb1,
    const float* __restrict__ g2, const float* __restrict__ bb2,
    float* __restrict__ out, int H) {
    constexpr int XT = TILE + 4, HT = TILE + 2;
    constexpr int XA = XT * XT, HA = HT * HT;
    __shared__ float xs[C][XA];
    __shared__ float h1[C][HA];
    __shared__ float msh[XA];

    int tid = threadIdx.x;
    int bid = blockIdx.x;
    int b = bid / (NTX * NTX);
    int t = bid % (NTX * NTX);
    int r0 = (t / NTX) * TILE, c0 = (t % NTX) * TILE;

    float gr[C], br[C];
    #pragma unroll
    for (int c = 0; c < C; ++c) { gr[c] = g1[c]; br[c] = bb1[c]; }

    for (int i = tid; i < XA; i += 256) {
        int py = i / XT, px = i % XT;
        int gy = r0 - 2 + py, gx = c0 - 2 + px;
        bool ok = (unsigned)gy < (unsigned)H && (unsigned)gx < (unsigned)H;
        float m = 0.0f;
        if (ok) m = mask[(size_t)(b * H + gy) * H + gx];
        msh[i] = m;
        if (m > 0.0f) {
            const float* ip = in + ((size_t)(b * H + gy) * H + gx) * C;
            #pragma unroll
            for (int c = 0; c < C; ++c)
                xs[c][i] = m * fmaxf(fmaf(ip[c], gr[c], br[c]), 0.0f);
        } else {
            #pragma unroll
            for (int c = 0; c < C; ++c) xs[c][i] = 0.0f;
        }
    }
    #pragma unroll
    for (int c = 0; c < C; ++c) { gr[c] = g2[c]; br[c] = bb2[c]; }
    __syncthreads();

    for (int pos = tid; pos < HA; pos += 256) {
        int py = pos / HT, px = pos % HT;
        float mc = msh[(py + 1) * XT + px + 1];
        float acc[C];
        #pragma unroll
        for (int co = 0; co < C; ++co) acc[co] = 0.0f;
        if (mc > 0.0f) {
            #pragma unroll
            for (int kh = 0; kh < 3; ++kh)
                #pragma unroll
                for (int kw = 0; kw < 3; ++kw) {
                    int pix = (py + kh) * XT + px + kw;
                    const float* wp = w1 + (kh * 3 + kw) * C * C;
                    #pragma unroll
                    for (int ci = 0; ci < C; ++ci) {
                        float xv = xs[ci][pix];
                        #pragma unroll
                        for (int co = 0; co < C; ++co)
                            acc[co] = fmaf(xv, wp[ci * C + co], acc[co]);
                    }
                }
        }
        #pragma unroll
        for (int co = 0; co < C; ++co)
            h1[co][pos] = mc * fmaxf(fmaf(acc[co] * mc, gr[co], br[co]), 0.0f);
    }
    __syncthreads();

    {
        int ty = tid / TILE, tx = tid % TILE;
        int gy = r0 + ty, gx = c0 + tx;
        if (gy < H && gx < H) {
            float mo = msh[(ty + 2) * XT + tx + 2];
            float acc[C];
            #pragma unroll
            for (int co = 0; co < C; ++co) acc[co] = 0.0f;
            if (mo > 0.0f) {
                #pragma unroll
                for (int kh = 0; kh < 3; ++kh)
                    #pragma unroll
                    for (int kw = 0; kw < 3; ++kw) {
                        int pix = (ty + kh) * HT + tx + kw;
                        const float* wp = w2 + (kh * 3 + kw) * C * C;
                        #pragma unroll
                        for (int ci = 0; ci < C; ++ci) {
                            float xv = h1[ci][pix];
                            #pragma unroll
                            for (int co = 0; co < C; ++co)
                                acc[co] = fmaf(xv, wp[ci * C + co], acc[co]);
                        }
                    }
            }
            const float* rp = in + ((size_t)(b * H + gy) * H + gx) * C;
            float* op = out + ((size_t)(b * H + gy) * H + gx) * C;
            #pragma unroll
            for (int j = 0; j < C; j += 4) {
                float4 r4 = *(const float4*)(rp + j);
                float4 o4;
                o4.x = fmaf(acc[j],     mo, r4.x);
                o4.y = fmaf(acc[j + 1], mo, r4.y);
                o4.z = fmaf(acc[j + 2], mo, r4.z);
                o4.w = fmaf(acc[j + 3], mo, r4.w);
                *(float4*)(op + j) = o4;
            }
        }
    }
}

// Fused conv: optionally bnrelu on input, conv, * mOut, [+ res].
template <int K, int CIN, int COUT, int COT, bool BN, bool RES>
__global__ __launch_bounds__(256) void fconv_kernel(
    const float* __restrict__ in, const float* __restrict__ w,
    const float* __restrict__ g, const float* __restrict__ bbn,
    const float* __restrict__ mIn, const float* __restrict__ mOut,
    const float* __restrict__ res, float* __restrict__ out,
    int Hin, int Hout, int stride, int pad) {
    const int Win = Hin, Wout = Hout;
    int npix = BATCH * Hout * Wout;
    int opix = blockIdx.x * 256 + threadIdx.x;
    if (opix >= npix) return;
    int co0 = blockIdx.y * COT;
    int wo = opix % Wout;
    int t = opix / Wout;
    int ho = t % Hout;
    int b  = t / Hout;

    float mo = mOut[opix];
    float* op = out + (size_t)opix * COUT + co0;
    if (mo <= 0.0f) {
        #pragma unroll
        for (int j = 0; j < COT; j += 4) {
            float4 r4 = RES ? *(const float4*)(res + (size_t)opix * COUT + co0 + j)
                            : make_float4(0,0,0,0);
            *(float4*)(op + j) = r4;
        }
        return;
    }
    float acc[COT];
    #pragma unroll
    for (int j = 0; j < COT; ++j) acc[j] = 0.0f;

    #pragma unroll
    for (int kh = 0; kh < K; ++kh) {
        int ih = ho * stride + kh - pad;
        if ((unsigned)ih >= (unsigned)Hin) continue;
        #pragma unroll
        for (int kw = 0; kw < K; ++kw) {
            int iw = wo * stride + kw - pad;
            if ((unsigned)iw >= (unsigned)Win) continue;
            int ipix = (b * Hin + ih) * Win + iw;
            float mi = 1.0f;
            if (BN) { mi = mIn[ipix]; if (mi <= 0.0f) continue; }
            const float* ip = in + (size_t)ipix * CIN;
            const float* wp = w + (kh * K + kw) * CIN * COUT + co0;
            #pragma unroll
            for (int ci = 0; ci < CIN; ci += 4) {
                float4 xv = *(const float4*)(ip + ci);
                if (BN) {
                    xv.x = mi * fmaxf(fmaf(xv.x, g[ci],     bbn[ci]),     0.0f);
                    xv.y = mi * fmaxf(fmaf(xv.y, g[ci + 1], bbn[ci + 1]), 0.0f);
                    xv.z = mi * fmaxf(fmaf(xv.z, g[ci + 2], bbn[ci + 2]), 0.0f);
                    xv.w = mi * fmaxf(fmaf(xv.w, g[ci + 3], bbn[ci + 3]), 0.0f);
                }
                #pragma unroll
                for (int j = 0; j < COT; ++j) {
                    acc[j] = fmaf(xv.x, wp[(ci    ) * COUT + j], acc[j]);
                    acc[j] = fmaf(xv.y, wp[(ci + 1) * COUT + j], acc[j]);
                    acc[j] = fmaf(xv.z, wp[(ci + 2) * COUT + j], acc[j]);
                    acc[j] = fmaf(xv.w, wp[(ci + 3) * COUT + j], acc[j]);
                }
            }
        }
    }
    #pragma unroll
    for (int j = 0; j < COT; j += 4) {
        float4 o4;
        o4.x = acc[j] * mo; o4.y = acc[j+1] * mo; o4.z = acc[j+2] * mo; o4.w = acc[j+3] * mo;
        if (RES) {
            float4 r4 = *(const float4*)(res + (size_t)opix * COUT + co0 + j);
            o4.x += r4.x; o4.y += r4.y; o4.z += r4.z; o4.w += r4.w;
        }
        *(float4*)(op + j) = o4;
    }
}

// Fused downsample stage (path x channel-group parallel):
//   m2 = maxpool3x3s2(mIn)  (written by blockIdx.y == 0)
//   path 0: outR = conv3x3s2(x) * m2 ; path 1: outA = conv3x3s2(bnrelu(x)) * m2
template <int CIN, int COUT, int COT>
__global__ __launch_bounds__(256) void strided_ra_kernel(
    const float* __restrict__ in,
    const float* __restrict__ wR, const float* __restrict__ wA,
    const float* __restrict__ g, const float* __restrict__ bbn,
    const float* __restrict__ mIn, float* __restrict__ mOutBuf,
    float* __restrict__ outR, float* __restrict__ outA,
    int Hin, int Hout) {
    constexpr int NG = COUT / COT;
    int npix = BATCH * Hout * Hout;
    int opix = blockIdx.x * 256 + threadIdx.x;
    if (opix >= npix) return;
    int path = blockIdx.y / NG;
    int co0  = (blockIdx.y % NG) * COT;
    int wo = opix % Hout;
    int t = opix / Hout;
    int ho = t % Hout;
    int b  = t / Hout;

    const float* wsel = path ? wA : wR;
    float acc[COT];
    #pragma unroll
    for (int j = 0; j < COT; ++j) acc[j] = 0.0f;
    float m2 = 0.0f;

    #pragma unroll
    for (int kh = 0; kh < 3; ++kh) {
        int ih = 2 * ho + kh;
        #pragma unroll
        for (int kw = 0; kw < 3; ++kw) {
            int iw = 2 * wo + kw;
            int ipix = (b * Hin + ih) * Hin + iw;
            float mi = mIn[ipix];
            if (mi <= 0.0f) continue;
            m2 = fmaxf(m2, mi);
            const float* ip = in + (size_t)ipix * CIN;
            const float* wp = wsel + (kh * 3 + kw) * CIN * COUT + co0;
            #pragma unroll
            for (int ci = 0; ci < CIN; ci += 4) {
                float4 xv = *(const float4*)(ip + ci);
                if (path) {
                    xv.x = mi * fmaxf(fmaf(xv.x, g[ci],     bbn[ci]),     0.0f);
                    xv.y = mi * fmaxf(fmaf(xv.y, g[ci + 1], bbn[ci + 1]), 0.0f);
                    xv.z = mi * fmaxf(fmaf(xv.z, g[ci + 2], bbn[ci + 2]), 0.0f);
                    xv.w = mi * fmaxf(fmaf(xv.w, g[ci + 3], bbn[ci + 3]), 0.0f);
                }
                #pragma unroll
                for (int j = 0; j < COT; ++j) {
                    acc[j] = fmaf(xv.x, wp[(ci    ) * COUT + j], acc[j]);
                    acc[j] = fmaf(xv.y, wp[(ci + 1) * COUT + j], acc[j]);
                    acc[j] = fmaf(xv.z, wp[(ci + 2) * COUT + j], acc[j]);
                    acc[j] = fmaf(xv.w, wp[(ci + 3) * COUT + j], acc[j]);
                }
            }
        }
    }
    if (blockIdx.y == 0) mOutBuf[opix] = m2;
    float* op = (path ? outA : outR) + (size_t)opix * COUT + co0;
    #pragma unroll
    for (int j = 0; j < COT; j += 4) {
        float4 o4;
        o4.x = acc[j] * m2; o4.y = acc[j+1] * m2; o4.z = acc[j+2] * m2; o4.w = acc[j+3] * m2;
        *(float4*)(op + j) = o4;
    }
}

// conv_last (K=5, 12->8, 32->64ch), kh-split for occupancy + LDS read-efficiency.
// Grid (BATCH, 2, 5): bz = kh slice (stages only rows kh..kh+7 = 12 KB LDS),
// by = co-half. 1280 blocks. Each thread: 64px lanes x 4 co-groups of 8 ->
// 160 ds_reads each feeding 8 FMAs (vs r9's 800 reads / 2 FMAs-per-read).
// Partials atomicAdd'ed into pre-zeroed accumulator.
__global__ __launch_bounds__(256) void conv_last_split_kernel(
    const float* __restrict__ in,   // (B,12,12,32) pre-bn
    const float* __restrict__ w,    // (5,5,32,64)
    const float* __restrict__ g, const float* __restrict__ bbn,
    const float* __restrict__ mIn,  // (B,12,12)
    const float* __restrict__ mOut, // (B,8,8)
    float* __restrict__ out) {      // (B,8,8,64) accumulator, pre-zeroed
    __shared__ float xs[32][96];    // rows kh..kh+7, 8x12 pixels, planar
    int b  = blockIdx.x;
    int kh = blockIdx.z;
    int tid = threadIdx.x;
    // stage rows kh..kh+7 with bnrelu fused
    for (int i = tid; i < 96; i += 256) {
        int gpix = b * 144 + (kh + i / 12) * 12 + (i % 12);
        float mi = mIn[gpix];
        const float* ip = in + (size_t)gpix * 32;
        if (mi > 0.0f) {
            #pragma unroll
            for (int c = 0; c < 32; c += 4) {
                float4 v = *(const float4*)(ip + c);
                xs[c][i]     = mi * fmaxf(fmaf(v.x, g[c],     bbn[c]),     0.0f);
                xs[c + 1][i] = mi * fmaxf(fmaf(v.y, g[c + 1], bbn[c + 1]), 0.0f);
                xs[c + 2][i] = mi * fmaxf(fmaf(v.z, g[c + 2], bbn[c + 2]), 0.0f);
                xs[c + 3][i] = mi * fmaxf(fmaf(v.w, g[c + 3], bbn[c + 3]), 0.0f);
            }
        } else {
            #pragma unroll
            for (int c = 0; c < 32; ++c) xs[c][i] = 0.0f;
        }
    }
    __syncthreads();
    int px = tid & 63;                          // lanes span px -> 2-way LDS (free)
    int co = blockIdx.y * 32 + (tid >> 6) * 8;  // wave-uniform -> s_load weights
    int ho = px >> 3, wo = px & 7;
    float mo = mOut[b * 64 + px];
    if (mo <= 0.0f) return;
    float acc[8];
    #pragma unroll
    for (int j = 0; j < 8; ++j) acc[j] = 0.0f;
    #pragma unroll
    for (int kw = 0; kw < 5; ++kw) {
        const float* wp = w + ((kh * 5 + kw) * 32) * 64 + co;
        int pix = ho * 12 + wo + kw;            // local row = ho (rows shifted by kh)
        #pragma unroll
        for (int ci = 0; ci < 32; ++ci) {
            float xv = xs[ci][pix];
            #pragma unroll
            for (int j = 0; j < 8; ++j)
                acc[j] = fmaf(xv, wp[ci * 64 + j], acc[j]);
        }
    }
    float* op = out + ((size_t)b * 64 + px) * 64 + co;
    #pragma unroll
    for (int j = 0; j < 8; ++j) atomicAdd(op + j, acc[j] * mo);
}

__global__ void pool_kernel(const float* __restrict__ in, float* __restrict__ out,
                            int Hin, int Win, int Hout, int Wout, int win, int stride) {
    int tid = blockIdx.x * blockDim.x + threadIdx.x;
    int total = BATCH * Hout * Wout;
    if (tid >= total) return;
    int wo = tid % Wout;
    int p = tid / Wout;
    int ho = p % Hout;
    int b  = p / Hout;
    float mx = 0.0f;
    for (int i = 0; i < win; ++i)
        for (int j = 0; j < win; ++j)
            mx = fmaxf(mx, in[(b * Hin + ho * stride + i) * Win + wo * stride + j]);
    out[tid] = mx;
}

// bnrelu(g17,b17) + flatten to NCHW-flat layout: xt[b][c*64+hw]
__global__ __launch_bounds__(256) void bn_tr_kernel(
    const float* __restrict__ x, const float* __restrict__ m,
    const float* __restrict__ g, const float* __restrict__ bb,
    float* __restrict__ xt) {
    int tid = blockIdx.x * 256 + threadIdx.x;
    if (tid >= BATCH * 4096) return;
    int c = tid & 63, hw = (tid >> 6) & 63, b = tid >> 12;
    float v = m[b * 64 + hw] * fmaxf(fmaf(x[tid], g[c], bb[c]), 0.0f);
    xt[((size_t)b << 12) + c * 64 + hw] = v;
}

// C[128,100] += xt[128,4096] . wl[100,4096]^T, split-K with atomics.
__global__ __launch_bounds__(256) void linear_gemm_kernel(
    const float* __restrict__ xt, const float* __restrict__ wl,
    float* __restrict__ out) {
    int o = blockIdx.x;
    int half = threadIdx.x >> 7;
    int b = threadIdx.x & 127;
    int k0 = blockIdx.y * 512 + half * 256;
    const float* xp = xt + ((size_t)b << 12) + k0;
    const float* wp = wl + o * 4096 + k0;
    float acc = 0.0f;
    #pragma unroll 16
    for (int k = 0; k < 256; k += 4) {
        float4 xv = *(const float4*)(xp + k);
        float4 wv = *(const float4*)(wp + k);
        acc = fmaf(xv.x, wv.x, acc); acc = fmaf(xv.y, wv.y, acc);
        acc = fmaf(xv.z, wv.z, acc); acc = fmaf(xv.w, wv.w, acc);
    }
    atomicAdd(&out[b * 100 + o], acc);
}

template <int K, int CIN, int COUT, int COT, bool BN, bool RES>
static inline void fconv(hipStream_t s, const float* in, const float* w,
                         const float* g, const float* bbn,
                         const float* mIn, const float* mOut, const float* res,
                         float* out, int Hin, int Hout, int stride, int pad) {
    int npix = BATCH * Hout * Hout;
    dim3 grid((npix + 255) / 256, COUT / COT);
    fconv_kernel<K, CIN, COUT, COT, BN, RES><<<grid, 256, 0, s>>>(
        in, w, g, bbn, mIn, mOut, res, out, Hin, Hout, stride, pad);
}

template <int CIN, int COUT, int COT>
static inline void strided_ra(hipStream_t s, const float* in, const float* wR, const float* wA,
                              const float* g, const float* bbn, const float* mIn,
                              float* mOutBuf, float* outR, float* outA, int Hin, int Hout) {
    int npix = BATCH * Hout * Hout;
    dim3 grid((npix + 255) / 256, 2 * (COUT / COT));
    strided_ra_kernel<CIN, COUT, COT><<<grid, 256, 0, s>>>(
        in, wR, wA, g, bbn, mIn, mOutBuf, outR, outA, Hin, Hout);
}

extern "C" void kernel_launch(void* const* d_in, const int* in_sizes, int n_in,
                              void* d_out, int out_size, void* d_ws, size_t ws_size,
                              hipStream_t stream) {
    const int*   loc   = (const int*)d_in[0];
    const int*   bidx  = (const int*)d_in[1];
    const float* feat  = (const float*)d_in[2];
    const float* gamma = (const float*)d_in[3];
    const float* beta  = (const float*)d_in[4];
    const float* Wconv0 = (const float*)d_in[5];
    const float* Wc1a = (const float*)d_in[6];
    const float* Wc1b = (const float*)d_in[7];
    const float* Wc2a = (const float*)d_in[8];
    const float* Wc2b = (const float*)d_in[9];
    const float* Wc3a = (const float*)d_in[10];
    const float* Wc3b = (const float*)d_in[11];
    const float* Wc3r = (const float*)d_in[12];
    const float* Wc4a = (const float*)d_in[13];
    const float* Wc4b = (const float*)d_in[14];
    const float* Wc5a = (const float*)d_in[15];
    const float* Wc5b = (const float*)d_in[16];
    const float* Wc5r = (const float*)d_in[17];
    const float* Wc6a = (const float*)d_in[18];
    const float* Wc6b = (const float*)d_in[19];
    const float* Wc7a = (const float*)d_in[20];
    const float* Wc7b = (const float*)d_in[21];
    const float* Wc7r = (const float*)d_in[22];
    const float* Wc8a = (const float*)d_in[23];
    const float* Wc8b = (const float*)d_in[24];
    const float* Wlast = (const float*)d_in[25];
    const float* wlin  = (const float*)d_in[26];

    const size_t SZB = (size_t)BATCH * 103 * 103 * 8;
    const size_t SZM = (size_t)BATCH * 103 * 103;
    float* b0 = (float*)d_ws;
    float* b1 = b0 + SZB;
    float* b2 = b1 + SZB;
    float* m0 = b2 + SZB;
    float* m1 = m0 + SZM;

    const float* G[18];
    const float* Bt[18];
    for (int i = 0; i < 18; ++i) { G[i] = gamma + OFFS[i]; Bt[i] = beta + OFFS[i]; }

    // scatter into xs(b1), ms(b2)
    {
        int n = BATCH * S * S;
        zero2_kernel<<<(n / 4 + 255) / 256, 256, 0, stream>>>((float4*)b1, (float4*)b2, n / 4);
        scatter_kernel<<<(NPTS + 255) / 256, 256, 0, stream>>>(loc, bidx, feat, b1, b2);
        int total = BATCH * 103 * 103;
        conv0_pool_kernel<<<(total + 255) / 256, 256, 0, stream>>>(b1, b2, Wconv0, b0, m0);
    }
    // x = b0 (103,103,8), mask = m0

    // c1, c2: fused residual blocks (planar LDS, C=8)
    resblock_kernel<8, 16, 7><<<dim3(7 * 7 * BATCH), 256, 0, stream>>>(
        b0, m0, Wc1a, Wc1b, G[0], Bt[0], G[1], Bt[1], b1, 103);
    resblock_kernel<8, 16, 7><<<dim3(7 * 7 * BATCH), 256, 0, stream>>>(
        b1, m0, Wc2a, Wc2b, G[2], Bt[2], G[3], Bt[3], b2, 103);
    // x = b2
    // c3 (stride2, 103->51, 8->16): full-width COT=16, 2-way path split only
    strided_ra<8, 16, 16>(stream, b2, Wc3r, Wc3a, G[4], Bt[4], m0, m1, b0, b1, 103, 51);
    fconv<3, 16, 16, 8, true, true >(stream, b1, Wc3b, G[5], Bt[5], m1, m1, b0, b2, 51, 51, 1, 1);
    // x = b2, mask = m1
    // c4 (fconv pair — resblock<16> measured worse, r7)
    fconv<3, 16, 16, 8, true, false>(stream, b2, Wc4a, G[6], Bt[6], m1, m1, nullptr, b0, 51, 51, 1, 1);
    fconv<3, 16, 16, 8, true, true >(stream, b0, Wc4b, G[7], Bt[7], m1, m1, b2,      b1, 51, 51, 1, 1);
    // x = b1
    // c5 (stride2, 51->25, 16->24): full-width COT=24
    strided_ra<16, 24, 24>(stream, b1, Wc5r, Wc5a, G[8], Bt[8], m1, m0, b0, b2, 51, 25);
    fconv<3, 24, 24, 8, true, true >(stream, b2, Wc5b, G[9], Bt[9], m0, m0, b0, b1, 25, 25, 1, 1);
    // x = b1, mask = m0
    // c6
    fconv<3, 24, 24, 8, true, false>(stream, b1, Wc6a, G[10], Bt[10], m0, m0, nullptr, b0, 25, 25, 1, 1);
    fconv<3, 24, 24, 8, true, true >(stream, b0, Wc6b, G[11], Bt[11], m0, m0, b1,      b2, 25, 25, 1, 1);
    // x = b2
    // c7 (stride2, 25->12, 24->32): COT=8
    strided_ra<24, 32, 8>(stream, b2, Wc7r, Wc7a, G[12], Bt[12], m0, m1, b0, b1, 25, 12);
    fconv<3, 32, 32, 4, true, true >(stream, b1, Wc7b, G[13], Bt[13], m1, m1, b0, b2, 12, 12, 1, 1);
    // x = b2, mask = m1
    // c8
    fconv<3, 32, 32, 4, true, false>(stream, b2, Wc8a, G[14], Bt[14], m1, m1, nullptr, b0, 12, 12, 1, 1);
    fconv<3, 32, 32, 4, true, true >(stream, b0, Wc8b, G[15], Bt[15], m1, m1, b2,      b1, 12, 12, 1, 1);
    // x = b1
    // tail: zero accumulator b0 (2 MB) + d_out, pool mask, kh-split conv_last,
    // bn_tr, split-K linear.
    zero_pair_kernel<<<(BATCH * 8 * 8 * 64 / 4 + 255) / 256, 256, 0, stream>>>(
        (float4*)b0, BATCH * 8 * 8 * 64 / 4, (float4*)d_out, BATCH * 100 / 4);
    pool_kernel<<<(BATCH * 64 + 255) / 256, 256, 0, stream>>>(m1, m0, 12, 12, 8, 8, 5, 1);
    conv_last_split_kernel<<<dim3(BATCH, 2, 5), 256, 0, stream>>>(
        b1, Wlast, G[16], Bt[16], m1, m0, b0);
    bn_tr_kernel<<<(BATCH * 4096 + 255) / 256, 256, 0, stream>>>(b0, m0, G[17], Bt[17], b2);
    linear_gemm_kernel<<<dim3(100, 8), 256, 0, stream>>>(b2, wlin, (float*)d_out);
}

// Round 11
// 841.527 us; speedup vs baseline: 1.0834x; 1.0834x over previous
//
#include <hip/hip_runtime.h>

#define S 207
#define BATCH 128
#define NPTS 256000

static const int OFFS[19] = {0,8,16,24,32,40,56,72,88,104,128,152,176,200,232,264,296,328,392};

__global__ void zero2_kernel(float4* __restrict__ a, float4* __restrict__ b, int n4) {
    int i = blockIdx.x * blockDim.x + threadIdx.x;
    if (i < n4) { a[i] = make_float4(0,0,0,0); b[i] = make_float4(0,0,0,0); }
}

__global__ void zero_kernel(float* __restrict__ p, int n) {
    int i = blockIdx.x * blockDim.x + threadIdx.x;
    if (i < n) p[i] = 0.0f;
}

__global__ void scatter_kernel(const int* __restrict__ loc, const int* __restrict__ bidx,
                               const float* __restrict__ feat,
                               float* __restrict__ xs, float* __restrict__ ms) {
    int t = blockIdx.x * blockDim.x + threadIdx.x;
    if (t >= NPTS) return;
    int b = bidx[t];
    int r = loc[2 * t];
    int c = loc[2 * t + 1];
    int idx = (b * S + r) * S + c;
    atomicAdd(&xs[idx], feat[t]);
    ms[idx] = 1.0f;
}

// Fused conv0(SAME)*m -> masked 3x2 maxpool. One thread per output pixel, all 8 channels.
__global__ __launch_bounds__(256) void conv0_pool_kernel(
    const float* __restrict__ xs, const float* __restrict__ ms,
    const float* __restrict__ w,   // (3,3,1,8)
    float* __restrict__ x1, float* __restrict__ m1) {
    const int Hout = 103;
    int opix = blockIdx.x * 256 + threadIdx.x;
    int total = BATCH * Hout * Hout;
    if (opix >= total) return;
    int wo = opix % Hout;
    int t = opix / Hout;
    int ho = t % Hout;
    int b  = t / Hout;

    float mv[3][3];
    float mwin = 0.0f;
    #pragma unroll
    for (int pi = 0; pi < 3; ++pi)
        #pragma unroll
        for (int pj = 0; pj < 3; ++pj) {
            float m = ms[(b * S + 2 * ho + pi) * S + 2 * wo + pj];
            mv[pi][pj] = m;
            mwin = fmaxf(mwin, m);
        }
    float* xp = x1 + (size_t)opix * 8;
    if (mwin <= 0.0f) {
        *(float4*)xp = make_float4(0,0,0,0);
        *(float4*)(xp + 4) = make_float4(0,0,0,0);
        m1[opix] = 0.0f;
        return;
    }
    float p[5][5];
    #pragma unroll
    for (int r = 0; r < 5; ++r) {
        int ii = 2 * ho - 1 + r;
        #pragma unroll
        for (int c = 0; c < 5; ++c) {
            int jj = 2 * wo - 1 + c;
            bool ok = ((unsigned)ii < (unsigned)S) && ((unsigned)jj < (unsigned)S);
            p[r][c] = ok ? xs[(b * S + ii) * S + jj] : 0.0f;
        }
    }
    float best[8];
    #pragma unroll
    for (int co = 0; co < 8; ++co) best[co] = -1e30f;
    #pragma unroll
    for (int pi = 0; pi < 3; ++pi)
        #pragma unroll
        for (int pj = 0; pj < 3; ++pj) {
            if (mv[pi][pj] > 0.0f) {
                float acc[8];
                #pragma unroll
                for (int co = 0; co < 8; ++co) acc[co] = 0.0f;
                #pragma unroll
                for (int kh = 0; kh < 3; ++kh)
                    #pragma unroll
                    for (int kw = 0; kw < 3; ++kw) {
                        float x = p[pi + kh][pj + kw];
                        #pragma unroll
                        for (int co = 0; co < 8; ++co)
                            acc[co] = fmaf(x, w[(kh * 3 + kw) * 8 + co], acc[co]);
                    }
                #pragma unroll
                for (int co = 0; co < 8; ++co) best[co] = fmaxf(best[co], acc[co]);
            }
        }
    *(float4*)xp = make_float4(best[0], best[1], best[2], best[3]);
    *(float4*)(xp + 4) = make_float4(best[4], best[5], best[6], best[7]);
    m1[opix] = 1.0f;
}

// Fused full residual block (stride 1, CIN==COUT==C), planar-LDS. C=8 only —
// measured: C=16 variant regresses (48 KB LDS -> 25% occ, 151 us; r7).
template <int C, int TILE, int NTX>
__global__ __launch_bounds__(256) void resblock_kernel(
    const float* __restrict__ in, const float* __restrict__ mask,
    const float* __restrict__ w1, const float* __restrict__ w2,
    const float* __restrict__ g1, const float* __restrict__ bb1,
    const float* __restrict__ g2, const float* __restrict__ bb2,
    float* __restrict__ out, int H) {
    constexpr int XT = TILE + 4, HT = TILE + 2;
    constexpr int XA = XT * XT, HA = HT * HT;
    __shared__ float xs[C][XA];
    __shared__ float h1[C][HA];
    __shared__ float msh[XA];

    int tid = threadIdx.x;
    int bid = blockIdx.x;
    int b = bid / (NTX * NTX);
    int t = bid % (NTX * NTX);
    int r0 = (t / NTX) * TILE, c0 = (t % NTX) * TILE;

    float gr[C], br[C];
    #pragma unroll
    for (int c = 0; c < C; ++c) { gr[c] = g1[c]; br[c] = bb1[c]; }

    for (int i = tid; i < XA; i += 256) {
        int py = i / XT, px = i % XT;
        int gy = r0 - 2 + py, gx = c0 - 2 + px;
        bool ok = (unsigned)gy < (unsigned)H && (unsigned)gx < (unsigned)H;
        float m = 0.0f;
        if (ok) m = mask[(size_t)(b * H + gy) * H + gx];
        msh[i] = m;
        if (m > 0.0f) {
            const float* ip = in + ((size_t)(b * H + gy) * H + gx) * C;
            #pragma unroll
            for (int c = 0; c < C; ++c)
                xs[c][i] = m * fmaxf(fmaf(ip[c], gr[c], br[c]), 0.0f);
        } else {
            #pragma unroll
            for (int c = 0; c < C; ++c) xs[c][i] = 0.0f;
        }
    }
    #pragma unroll
    for (int c = 0; c < C; ++c) { gr[c] = g2[c]; br[c] = bb2[c]; }
    __syncthreads();

    for (int pos = tid; pos < HA; pos += 256) {
        int py = pos / HT, px = pos % HT;
        float mc = msh[(py + 1) * XT + px + 1];
        float acc[C];
        #pragma unroll
        for (int co = 0; co < C; ++co) acc[co] = 0.0f;
        if (mc > 0.0f) {
            #pragma unroll
            for (int kh = 0; kh < 3; ++kh)
                #pragma unroll
                for (int kw = 0; kw < 3; ++kw) {
                    int pix = (py + kh) * XT + px + kw;
                    const float* wp = w1 + (kh * 3 + kw) * C * C;
                    #pragma unroll
                    for (int ci = 0; ci < C; ++ci) {
                        float xv = xs[ci][pix];
                        #pragma unroll
                        for (int co = 0; co < C; ++co)
                            acc[co] = fmaf(xv, wp[ci * C + co], acc[co]);
                    }
                }
        }
        #pragma unroll
        for (int co = 0; co < C; ++co)
            h1[co][pos] = mc * fmaxf(fmaf(acc[co] * mc, gr[co], br[co]), 0.0f);
    }
    __syncthreads();

    {
        int ty = tid / TILE, tx = tid % TILE;
        int gy = r0 + ty, gx = c0 + tx;
        if (gy < H && gx < H) {
            float mo = msh[(ty + 2) * XT + tx + 2];
            float acc[C];
            #pragma unroll
            for (int co = 0; co < C; ++co) acc[co] = 0.0f;
            if (mo > 0.0f) {
                #pragma unroll
                for (int kh = 0; kh < 3; ++kh)
                    #pragma unroll
                    for (int kw = 0; kw < 3; ++kw) {
                        int pix = (ty + kh) * HT + tx + kw;
                        const float* wp = w2 + (kh * 3 + kw) * C * C;
                        #pragma unroll
                        for (int ci = 0; ci < C; ++ci) {
                            float xv = h1[ci][pix];
                            #pragma unroll
                            for (int co = 0; co < C; ++co)
                                acc[co] = fmaf(xv, wp[ci * C + co], acc[co]);
                        }
                    }
            }
            const float* rp = in + ((size_t)(b * H + gy) * H + gx) * C;
            float* op = out + ((size_t)(b * H + gy) * H + gx) * C;
            #pragma unroll
            for (int j = 0; j < C; j += 4) {
                float4 r4 = *(const float4*)(rp + j);
                float4 o4;
                o4.x = fmaf(acc[j],     mo, r4.x);
                o4.y = fmaf(acc[j + 1], mo, r4.y);
                o4.z = fmaf(acc[j + 2], mo, r4.z);
                o4.w = fmaf(acc[j + 3], mo, r4.w);
                *(float4*)(op + j) = o4;
            }
        }
    }
}

// Fused conv: optionally bnrelu on input, conv, * mOut, [+ res].
template <int K, int CIN, int COUT, int COT, bool BN, bool RES>
__global__ __launch_bounds__(256) void fconv_kernel(
    const float* __restrict__ in, const float* __restrict__ w,
    const float* __restrict__ g, const float* __restrict__ bbn,
    const float* __restrict__ mIn, const float* __restrict__ mOut,
    const float* __restrict__ res, float* __restrict__ out,
    int Hin, int Hout, int stride, int pad) {
    const int Win = Hin, Wout = Hout;
    int npix = BATCH * Hout * Wout;
    int opix = blockIdx.x * 256 + threadIdx.x;
    if (opix >= npix) return;
    int co0 = blockIdx.y * COT;
    int wo = opix % Wout;
    int t = opix / Wout;
    int ho = t % Hout;
    int b  = t / Hout;

    float mo = mOut[opix];
    float* op = out + (size_t)opix * COUT + co0;
    if (mo <= 0.0f) {
        #pragma unroll
        for (int j = 0; j < COT; j += 4) {
            float4 r4 = RES ? *(const float4*)(res + (size_t)opix * COUT + co0 + j)
                            : make_float4(0,0,0,0);
            *(float4*)(op + j) = r4;
        }
        return;
    }
    float acc[COT];
    #pragma unroll
    for (int j = 0; j < COT; ++j) acc[j] = 0.0f;

    #pragma unroll
    for (int kh = 0; kh < K; ++kh) {
        int ih = ho * stride + kh - pad;
        if ((unsigned)ih >= (unsigned)Hin) continue;
        #pragma unroll
        for (int kw = 0; kw < K; ++kw) {
            int iw = wo * stride + kw - pad;
            if ((unsigned)iw >= (unsigned)Win) continue;
            int ipix = (b * Hin + ih) * Win + iw;
            float mi = 1.0f;
            if (BN) { mi = mIn[ipix]; if (mi <= 0.0f) continue; }
            const float* ip = in + (size_t)ipix * CIN;
            const float* wp = w + (kh * K + kw) * CIN * COUT + co0;
            #pragma unroll
            for (int ci = 0; ci < CIN; ci += 4) {
                float4 xv = *(const float4*)(ip + ci);
                if (BN) {
                    xv.x = mi * fmaxf(fmaf(xv.x, g[ci],     bbn[ci]),     0.0f);
                    xv.y = mi * fmaxf(fmaf(xv.y, g[ci + 1], bbn[ci + 1]), 0.0f);
                    xv.z = mi * fmaxf(fmaf(xv.z, g[ci + 2], bbn[ci + 2]), 0.0f);
                    xv.w = mi * fmaxf(fmaf(xv.w, g[ci + 3], bbn[ci + 3]), 0.0f);
                }
                #pragma unroll
                for (int j = 0; j < COT; ++j) {
                    acc[j] = fmaf(xv.x, wp[(ci    ) * COUT + j], acc[j]);
                    acc[j] = fmaf(xv.y, wp[(ci + 1) * COUT + j], acc[j]);
                    acc[j] = fmaf(xv.z, wp[(ci + 2) * COUT + j], acc[j]);
                    acc[j] = fmaf(xv.w, wp[(ci + 3) * COUT + j], acc[j]);
                }
            }
        }
    }
    #pragma unroll
    for (int j = 0; j < COT; j += 4) {
        float4 o4;
        o4.x = acc[j] * mo; o4.y = acc[j+1] * mo; o4.z = acc[j+2] * mo; o4.w = acc[j+3] * mo;
        if (RES) {
            float4 r4 = *(const float4*)(res + (size_t)opix * COUT + co0 + j);
            o4.x += r4.x; o4.y += r4.y; o4.z += r4.z; o4.w += r4.w;
        }
        *(float4*)(op + j) = o4;
    }
}

// Fused downsample stage (path x channel-group parallel):
//   m2 = maxpool3x3s2(mIn)  (written by blockIdx.y == 0)
//   path 0: outR = conv3x3s2(x) * m2 ; path 1: outA = conv3x3s2(bnrelu(x)) * m2
template <int CIN, int COUT, int COT>
__global__ __launch_bounds__(256) void strided_ra_kernel(
    const float* __restrict__ in,
    const float* __restrict__ wR, const float* __restrict__ wA,
    const float* __restrict__ g, const float* __restrict__ bbn,
    const float* __restrict__ mIn, float* __restrict__ mOutBuf,
    float* __restrict__ outR, float* __restrict__ outA,
    int Hin, int Hout) {
    constexpr int NG = COUT / COT;
    int npix = BATCH * Hout * Hout;
    int opix = blockIdx.x * 256 + threadIdx.x;
    if (opix >= npix) return;
    int path = blockIdx.y / NG;
    int co0  = (blockIdx.y % NG) * COT;
    int wo = opix % Hout;
    int t = opix / Hout;
    int ho = t % Hout;
    int b  = t / Hout;

    const float* wsel = path ? wA : wR;
    float acc[COT];
    #pragma unroll
    for (int j = 0; j < COT; ++j) acc[j] = 0.0f;
    float m2 = 0.0f;

    #pragma unroll
    for (int kh = 0; kh < 3; ++kh) {
        int ih = 2 * ho + kh;
        #pragma unroll
        for (int kw = 0; kw < 3; ++kw) {
            int iw = 2 * wo + kw;
            int ipix = (b * Hin + ih) * Hin + iw;
            float mi = mIn[ipix];
            if (mi <= 0.0f) continue;
            m2 = fmaxf(m2, mi);
            const float* ip = in + (size_t)ipix * CIN;
            const float* wp = wsel + (kh * 3 + kw) * CIN * COUT + co0;
            #pragma unroll
            for (int ci = 0; ci < CIN; ci += 4) {
                float4 xv = *(const float4*)(ip + ci);
                if (path) {
                    xv.x = mi * fmaxf(fmaf(xv.x, g[ci],     bbn[ci]),     0.0f);
                    xv.y = mi * fmaxf(fmaf(xv.y, g[ci + 1], bbn[ci + 1]), 0.0f);
                    xv.z = mi * fmaxf(fmaf(xv.z, g[ci + 2], bbn[ci + 2]), 0.0f);
                    xv.w = mi * fmaxf(fmaf(xv.w, g[ci + 3], bbn[ci + 3]), 0.0f);
                }
                #pragma unroll
                for (int j = 0; j < COT; ++j) {
                    acc[j] = fmaf(xv.x, wp[(ci    ) * COUT + j], acc[j]);
                    acc[j] = fmaf(xv.y, wp[(ci + 1) * COUT + j], acc[j]);
                    acc[j] = fmaf(xv.z, wp[(ci + 2) * COUT + j], acc[j]);
                    acc[j] = fmaf(xv.w, wp[(ci + 3) * COUT + j], acc[j]);
                }
            }
        }
    }
    if (blockIdx.y == 0) mOutBuf[opix] = m2;
    float* op = (path ? outA : outR) + (size_t)opix * COUT + co0;
    #pragma unroll
    for (int j = 0; j < COT; j += 4) {
        float4 o4;
        o4.x = acc[j] * m2; o4.y = acc[j+1] * m2; o4.z = acc[j+2] * m2; o4.w = acc[j+3] * m2;
        *(float4*)(op + j) = o4;
    }
}

// conv_last, COT=2 for grid parallelism: 1024 blocks (vs 512 at COT=4 -> 80 us,
// grid-limited 2 blocks/CU). Static shape K=5, 12->8, no atomics (r10: 13M
// atomics -> 84 MB HBM RMW traffic, 181 us). Weight rows wave-uniform.
__global__ __launch_bounds__(256) void conv_last_f2_kernel(
    const float* __restrict__ in,   // (B,12,12,32) pre-bn
    const float* __restrict__ w,    // (5,5,32,64)
    const float* __restrict__ g, const float* __restrict__ bbn,
    const float* __restrict__ mIn,  // (B,12,12)
    const float* __restrict__ mOut, // (B,8,8)
    float* __restrict__ out) {      // (B,8,8,64)
    int opix = blockIdx.x * 256 + threadIdx.x;   // 8192
    int co = blockIdx.y * 2;                     // wave-uniform
    int wo = opix & 7;
    int t = opix >> 3;
    int ho = t & 7;
    int b  = t >> 3;
    float mo = mOut[opix];
    float* op = out + (size_t)opix * 64 + co;
    if (mo <= 0.0f) { *(float2*)op = make_float2(0.0f, 0.0f); return; }
    float a0 = 0.0f, a1 = 0.0f;
    #pragma unroll
    for (int kh = 0; kh < 5; ++kh) {
        int ih = ho + kh;                        // 0..11, in range
        #pragma unroll
        for (int kw = 0; kw < 5; ++kw) {
            int iw = wo + kw;
            int ipix = (b * 12 + ih) * 12 + iw;
            float mi = mIn[ipix];
            if (mi <= 0.0f) continue;
            const float* ip = in + (size_t)ipix * 32;
            const float* wp = w + (kh * 5 + kw) * 2048 + co;
            #pragma unroll
            for (int ci = 0; ci < 32; ci += 4) {
                float4 xv = *(const float4*)(ip + ci);
                xv.x = mi * fmaxf(fmaf(xv.x, g[ci],     bbn[ci]),     0.0f);
                xv.y = mi * fmaxf(fmaf(xv.y, g[ci + 1], bbn[ci + 1]), 0.0f);
                xv.z = mi * fmaxf(fmaf(xv.z, g[ci + 2], bbn[ci + 2]), 0.0f);
                xv.w = mi * fmaxf(fmaf(xv.w, g[ci + 3], bbn[ci + 3]), 0.0f);
                a0 = fmaf(xv.x, wp[(ci    ) * 64], a0); a1 = fmaf(xv.x, wp[(ci    ) * 64 + 1], a1);
                a0 = fmaf(xv.y, wp[(ci + 1) * 64], a0); a1 = fmaf(xv.y, wp[(ci + 1) * 64 + 1], a1);
                a0 = fmaf(xv.z, wp[(ci + 2) * 64], a0); a1 = fmaf(xv.z, wp[(ci + 2) * 64 + 1], a1);
                a0 = fmaf(xv.w, wp[(ci + 3) * 64], a0); a1 = fmaf(xv.w, wp[(ci + 3) * 64 + 1], a1);
            }
        }
    }
    *(float2*)op = make_float2(a0 * mo, a1 * mo);
}

__global__ void pool_kernel(const float* __restrict__ in, float* __restrict__ out,
                            int Hin, int Win, int Hout, int Wout, int win, int stride) {
    int tid = blockIdx.x * blockDim.x + threadIdx.x;
    int total = BATCH * Hout * Wout;
    if (tid >= total) return;
    int wo = tid % Wout;
    int p = tid / Wout;
    int ho = p % Hout;
    int b  = p / Hout;
    float mx = 0.0f;
    for (int i = 0; i < win; ++i)
        for (int j = 0; j < win; ++j)
            mx = fmaxf(mx, in[(b * Hin + ho * stride + i) * Win + wo * stride + j]);
    out[tid] = mx;
}

// bnrelu(g17,b17) + flatten to NCHW-flat layout: xt[b][c*64+hw]
__global__ __launch_bounds__(256) void bn_tr_kernel(
    const float* __restrict__ x, const float* __restrict__ m,
    const float* __restrict__ g, const float* __restrict__ bb,
    float* __restrict__ xt) {
    int tid = blockIdx.x * 256 + threadIdx.x;
    if (tid >= BATCH * 4096) return;
    int c = tid & 63, hw = (tid >> 6) & 63, b = tid >> 12;
    float v = m[b * 64 + hw] * fmaxf(fmaf(x[tid], g[c], bb[c]), 0.0f);
    xt[((size_t)b << 12) + c * 64 + hw] = v;
}

// C[128,100] += xt[128,4096] . wl[100,4096]^T, split-K with atomics (~100k ops: fine).
__global__ __launch_bounds__(256) void linear_gemm_kernel(
    const float* __restrict__ xt, const float* __restrict__ wl,
    float* __restrict__ out) {
    int o = blockIdx.x;
    int half = threadIdx.x >> 7;
    int b = threadIdx.x & 127;
    int k0 = blockIdx.y * 512 + half * 256;
    const float* xp = xt + ((size_t)b << 12) + k0;
    const float* wp = wl + o * 4096 + k0;
    float acc = 0.0f;
    #pragma unroll 16
    for (int k = 0; k < 256; k += 4) {
        float4 xv = *(const float4*)(xp + k);
        float4 wv = *(const float4*)(wp + k);
        acc = fmaf(xv.x, wv.x, acc); acc = fmaf(xv.y, wv.y, acc);
        acc = fmaf(xv.z, wv.z, acc); acc = fmaf(xv.w, wv.w, acc);
    }
    atomicAdd(&out[b * 100 + o], acc);
}

template <int K, int CIN, int COUT, int COT, bool BN, bool RES>
static inline void fconv(hipStream_t s, const float* in, const float* w,
                         const float* g, const float* bbn,
                         const float* mIn, const float* mOut, const float* res,
                         float* out, int Hin, int Hout, int stride, int pad) {
    int npix = BATCH * Hout * Hout;
    dim3 grid((npix + 255) / 256, COUT / COT);
    fconv_kernel<K, CIN, COUT, COT, BN, RES><<<grid, 256, 0, s>>>(
        in, w, g, bbn, mIn, mOut, res, out, Hin, Hout, stride, pad);
}

template <int CIN, int COUT, int COT>
static inline void strided_ra(hipStream_t s, const float* in, const float* wR, const float* wA,
                              const float* g, const float* bbn, const float* mIn,
                              float* mOutBuf, float* outR, float* outA, int Hin, int Hout) {
    int npix = BATCH * Hout * Hout;
    dim3 grid((npix + 255) / 256, 2 * (COUT / COT));
    strided_ra_kernel<CIN, COUT, COT><<<grid, 256, 0, s>>>(
        in, wR, wA, g, bbn, mIn, mOutBuf, outR, outA, Hin, Hout);
}

extern "C" void kernel_launch(void* const* d_in, const int* in_sizes, int n_in,
                              void* d_out, int out_size, void* d_ws, size_t ws_size,
                              hipStream_t stream) {
    const int*   loc   = (const int*)d_in[0];
    const int*   bidx  = (const int*)d_in[1];
    const float* feat  = (const float*)d_in[2];
    const float* gamma = (const float*)d_in[3];
    const float* beta  = (const float*)d_in[4];
    const float* Wconv0 = (const float*)d_in[5];
    const float* Wc1a = (const float*)d_in[6];
    const float* Wc1b = (const float*)d_in[7];
    const float* Wc2a = (const float*)d_in[8];
    const float* Wc2b = (const float*)d_in[9];
    const float* Wc3a = (const float*)d_in[10];
    const float* Wc3b = (const float*)d_in[11];
    const float* Wc3r = (const float*)d_in[12];
    const float* Wc4a = (const float*)d_in[13];
    const float* Wc4b = (const float*)d_in[14];
    const float* Wc5a = (const float*)d_in[15];
    const float* Wc5b = (const float*)d_in[16];
    const float* Wc5r = (const float*)d_in[17];
    const float* Wc6a = (const float*)d_in[18];
    const float* Wc6b = (const float*)d_in[19];
    const float* Wc7a = (const float*)d_in[20];
    const float* Wc7b = (const float*)d_in[21];
    const float* Wc7r = (const float*)d_in[22];
    const float* Wc8a = (const float*)d_in[23];
    const float* Wc8b = (const float*)d_in[24];
    const float* Wlast = (const float*)d_in[25];
    const float* wlin  = (const float*)d_in[26];

    const size_t SZB = (size_t)BATCH * 103 * 103 * 8;
    const size_t SZM = (size_t)BATCH * 103 * 103;
    float* b0 = (float*)d_ws;
    float* b1 = b0 + SZB;
    float* b2 = b1 + SZB;
    float* m0 = b2 + SZB;
    float* m1 = m0 + SZM;

    const float* G[18];
    const float* Bt[18];
    for (int i = 0; i < 18; ++i) { G[i] = gamma + OFFS[i]; Bt[i] = beta + OFFS[i]; }

    // scatter into xs(b1), ms(b2)
    {
        int n = BATCH * S * S;
        zero2_kernel<<<(n / 4 + 255) / 256, 256, 0, stream>>>((float4*)b1, (float4*)b2, n / 4);
        scatter_kernel<<<(NPTS + 255) / 256, 256, 0, stream>>>(loc, bidx, feat, b1, b2);
        int total = BATCH * 103 * 103;
        conv0_pool_kernel<<<(total + 255) / 256, 256, 0, stream>>>(b1, b2, Wconv0, b0, m0);
    }
    // x = b0 (103,103,8), mask = m0

    // c1, c2: fused residual blocks (planar LDS, C=8)
    resblock_kernel<8, 16, 7><<<dim3(7 * 7 * BATCH), 256, 0, stream>>>(
        b0, m0, Wc1a, Wc1b, G[0], Bt[0], G[1], Bt[1], b1, 103);
    resblock_kernel<8, 16, 7><<<dim3(7 * 7 * BATCH), 256, 0, stream>>>(
        b1, m0, Wc2a, Wc2b, G[2], Bt[2], G[3], Bt[3], b2, 103);
    // x = b2
    // c3 (stride2, 103->51, 8->16): full-width COT=16, 2-way path split only
    strided_ra<8, 16, 16>(stream, b2, Wc3r, Wc3a, G[4], Bt[4], m0, m1, b0, b1, 103, 51);
    fconv<3, 16, 16, 8, true, true >(stream, b1, Wc3b, G[5], Bt[5], m1, m1, b0, b2, 51, 51, 1, 1);
    // x = b2, mask = m1
    // c4 (fconv pair — resblock<16> measured worse, r7)
    fconv<3, 16, 16, 8, true, false>(stream, b2, Wc4a, G[6], Bt[6], m1, m1, nullptr, b0, 51, 51, 1, 1);
    fconv<3, 16, 16, 8, true, true >(stream, b0, Wc4b, G[7], Bt[7], m1, m1, b2,      b1, 51, 51, 1, 1);
    // x = b1
    // c5 (stride2, 51->25, 16->24): full-width COT=24
    strided_ra<16, 24, 24>(stream, b1, Wc5r, Wc5a, G[8], Bt[8], m1, m0, b0, b2, 51, 25);
    fconv<3, 24, 24, 8, true, true >(stream, b2, Wc5b, G[9], Bt[9], m0, m0, b0, b1, 25, 25, 1, 1);
    // x = b1, mask = m0
    // c6
    fconv<3, 24, 24, 8, true, false>(stream, b1, Wc6a, G[10], Bt[10], m0, m0, nullptr, b0, 25, 25, 1, 1);
    fconv<3, 24, 24, 8, true, true >(stream, b0, Wc6b, G[11], Bt[11], m0, m0, b1,      b2, 25, 25, 1, 1);
    // x = b2
    // c7 (stride2, 25->12, 24->32): COT=8
    strided_ra<24, 32, 8>(stream, b2, Wc7r, Wc7a, G[12], Bt[12], m0, m1, b0, b1, 25, 12);
    fconv<3, 32, 32, 4, true, true >(stream, b1, Wc7b, G[13], Bt[13], m1, m1, b0, b2, 12, 12, 1, 1);
    // x = b2, mask = m1
    // c8
    fconv<3, 32, 32, 4, true, false>(stream, b2, Wc8a, G[14], Bt[14], m1, m1, nullptr, b0, 12, 12, 1, 1);
    fconv<3, 32, 32, 4, true, true >(stream, b0, Wc8b, G[15], Bt[15], m1, m1, b2,      b1, 12, 12, 1, 1);
    // x = b1
    // tail: pool mask, COT=2 conv_last (1024 blocks), bn_tr, zero out, split-K linear
    pool_kernel<<<(BATCH * 64 + 255) / 256, 256, 0, stream>>>(m1, m0, 12, 12, 8, 8, 5, 1);
    conv_last_f2_kernel<<<dim3(BATCH * 64 / 256, 32), 256, 0, stream>>>(
        b1, Wlast, G[16], Bt[16], m1, m0, b0);
    bn_tr_kernel<<<(BATCH * 4096 + 255) / 256, 256, 0, stream>>>(b0, m0, G[17], Bt[17], b2);
    zero_kernel<<<(BATCH * 100 + 255) / 256, 256, 0, stream>>>((float*)d_out, BATCH * 100);
    linear_gemm_kernel<<<dim3(100, 8), 256, 0, stream>>>(b2, wlin, (float*)d_out);
}